// Round 10
// baseline (403.588 us; speedup 1.0000x reference)
//
#include <hip/hip_runtime.h>
#include <cstdint>
#include <cstddef>

#define B_ 4
#define C_ 512
#define T_ 2048
#define S_ 2048
#define EPSF 1e-5f

typedef __bf16 bf16;
typedef __attribute__((ext_vector_type(8))) __bf16 bf16x8;
typedef __attribute__((ext_vector_type(4))) float f32x4;

__device__ __forceinline__ bf16 f2b(float f){ return (bf16)f; }
__device__ __forceinline__ float b2f(bf16 h){ return (float)h; }

__device__ __forceinline__ void gl_lds16(const void* g, void* l){
  __builtin_amdgcn_global_load_lds((__attribute__((address_space(1))) void*)(g),
                                   (__attribute__((address_space(3))) void*)(l), 16, 0, 0);
}

__device__ __forceinline__ float wave_sum(float v){
#pragma unroll
  for (int o = 32; o; o >>= 1) v += __shfl_xor(v, o, 64);
  return v;
}
__device__ __forceinline__ float wave_max(float v){
#pragma unroll
  for (int o = 32; o; o >>= 1) v = fmaxf(v, __shfl_xor(v, o, 64));
  return v;
}

// ---------------------------------------------------------------------------
// NT GEMM: C[m,n] = sum_k A[m,k]*B[n,k], both operands k-contiguous (bf16),
// fp32 MFMA accum. Tile 128 x (TNW*32), BK=64, 256 threads (2x2 waves).
// z-batched: A offset (z/zdivA)*sA, B offset (z%zmodB)*sB, C offset z*sC.
// GX/GY/NZ > 0: launched as flat 1D grid of GX*GY*NZ blocks with XCD-chunked
// decode — xcd=bid&7 owns a fixed z-slab subset so same-z blocks co-reside
// on one XCD and their shared A/B panels stay L2-hot (r5-verified: qk FETCH
// 79->24.7 MB). Bijective remap; no numerics change.
// EPI 0: bf16 store (acc*scale + cbias[n])
// EPI 2: f32 store relu(acc*rs[m%?]+rsh[..]) + fused per-row sum/sum^2 atomics
// EPI 3: no store — per-column sum^2 over m of acc*rlinv[row] (rlinv=1/l)
//        into osum2 only (mean-sum comes from colsum identity in vv_fin)
//        + fused colsum: ocol[t] += sum_s lA[s,t]*rlinv[s] for owned K-steps
//        (block bx owns K-steps with (k0/64)%4 == bx; exact 1x coverage)
// EPI 4: bf16 store exp(acc) + per-row partial-sum atomics into osum (l)
// EPI 5: bf16 store acc*rs[z,m] + rsh[z,m]*cbias[z,n]  (norm-fold epilogue)
// ---------------------------------------------------------------------------
template<int EPI, int TNW, int GX = 0, int GY = 0, int NZ = 0>
__global__ void __launch_bounds__(256) gemm_nt(
    const bf16* __restrict__ A, const bf16* __restrict__ Bm, void* __restrict__ Cout,
    int K, int lda, int ldb, int ldc,
    long long sA, long long sB, long long sC, long long sCb,
    int zdivA, int zmodB, float scale,
    const float* __restrict__ rs, const float* __restrict__ rsh,
    const float* __restrict__ cbias,
    float* __restrict__ osum, float* __restrict__ osum2, long long sRs,
    float* __restrict__ ocol)
{
  constexpr int TN = TNW*32;
  __shared__ alignas(16) bf16 lA[128*64];
  __shared__ alignas(16) bf16 lB[TN*64];
  __shared__ float redcs[EPI == 3 ? 32*68 : 1];   // colsum scratch (padded)
  const int tid = threadIdx.x;

  int bxv, byv, z;
  if constexpr (GX > 0) {
    const int bid = blockIdx.x;
    const int xcd = bid & 7, slot = bid >> 3;
    constexpr int NB  = GX*GY;                    // blocks per z
    constexpr int ZPX = (NZ >= 8) ? NZ/8 : 1;     // z per xcd
    constexpr int XPZ = (NZ >= 8) ? 1 : 8/NZ;     // xcds per z
    z = (xcd / XPZ) * ZPX + ((ZPX > 1) ? slot / NB : 0);
    const int inner = (ZPX > 1) ? (slot % NB)
                                : (slot + (xcd % XPZ) * (NB / XPZ));
    bxv = inner % GX; byv = inner / GX;
  } else {
    bxv = blockIdx.x; byv = blockIdx.y; z = blockIdx.z;
  }

  const bf16* Ab = A + (long long)(z / zdivA) * sA;
  const bf16* Bb = Bm + (long long)(z % zmodB) * sB;
  const int m0 = byv*128, n0 = bxv*TN;
  const int lane = tid & 63, wvi = tid >> 6;
  const int wm = wvi >> 1, wn = wvi & 1;

  f32x4 acc[4][TNW] = {};

  // loader: thread stages one 16B chunk/iter; XOR-swizzle k-chunk by (row&7)
  const int lrow = tid >> 3;
  const int lcol = ((tid ^ lrow) & 7) * 8;
  const bf16* pa = Ab + (long long)(m0 + lrow)*lda + lcol;
  const bf16* pb = Bb + (long long)(n0 + lrow)*ldb + lcol;
  char* sa = (char*)lA + tid*16;
  char* sb = (char*)lB + tid*16;

  // colsum: thread (g = tid>>3, ph = tid&7) handles rows g*4..g*4+3, logical
  // k-chunk ph of the staged A-tile. Preload 1/l for its 4 rows.
  const int csg = tid >> 3, csph = tid & 7;
  float linv4[4];
  if (EPI == 3) {
#pragma unroll
    for (int rr = 0; rr < 4; ++rr)
      linv4[rr] = 1.f / rs[(long long)z*sRs + (m0 + csg*4 + rr)];
  }

  for (int k0 = 0; k0 < K; k0 += 64) {
#pragma unroll
    for (int it = 0; it < 4; ++it)
      gl_lds16(pa + (long long)it*32*lda + k0, sa + it*4096);
#pragma unroll
    for (int it = 0; it < TNW; ++it)
      gl_lds16(pb + (long long)it*32*ldb + k0, sb + it*4096);
    __syncthreads();
#pragma unroll
    for (int ks = 0; ks < 2; ++ks) {
      const int kq = ks*4 + (lane >> 4);
      bf16x8 af[4], bfr[TNW];
#pragma unroll
      for (int mt = 0; mt < 4; ++mt) {
        int r = wm*64 + mt*16 + (lane & 15);
        af[mt] = *(const bf16x8*)&lA[r*64 + ((kq ^ (r & 7))*8)];
      }
#pragma unroll
      for (int nt = 0; nt < TNW; ++nt) {
        int r = wn*(TNW*16) + nt*16 + (lane & 15);
        bfr[nt] = *(const bf16x8*)&lB[r*64 + ((kq ^ (r & 7))*8)];
      }
#pragma unroll
      for (int mt = 0; mt < 4; ++mt)
#pragma unroll
        for (int nt = 0; nt < TNW; ++nt)
          acc[mt][nt] = __builtin_amdgcn_mfma_f32_16x16x32_bf16(af[mt], bfr[nt], acc[mt][nt], 0, 0, 0);
    }
    bool own = false;
    if (EPI == 3) {
      own = ((k0 >> 6) & 3) == bxv;
      if (own) {
        // weighted column sums of this A-tile (P rows s = m0+r, cols k0+..)
        float part[8] = {0.f,0.f,0.f,0.f,0.f,0.f,0.f,0.f};
#pragma unroll
        for (int rr = 0; rr < 4; ++rr) {
          const int r = csg*4 + rr;
          bf16x8 v = *(const bf16x8*)&lA[r*64 + ((csph ^ (r & 7))*8)];
          const float li = linv4[rr];
#pragma unroll
          for (int j = 0; j < 8; ++j) part[j] += b2f(v[j]) * li;
        }
#pragma unroll
        for (int j = 0; j < 8; ++j) redcs[csg*68 + csph*8 + j] = part[j];
      }
    }
    __syncthreads();
    if (EPI == 3) {
      if (own && tid < 64) {
        float s = 0.f;
#pragma unroll
        for (int g2 = 0; g2 < 32; ++g2) s += redcs[g2*68 + tid];
        atomicAdd(&ocol[(long long)z*lda + k0 + tid], s);
      }
    }
  }

  if (EPI == 3) {
    // per-column sum^2 over m of acc * (1/l[row]); no C store; no mean-sum
    // (meanc = (1/S) sum_t cs[t]*V[c,t] in vv_fin — summation-order swap).
    // reduction scratch aliased onto dead lA (loop ended with syncthreads).
    float* red2 = (float*)lA;                 // [4][TNW][16]
    const int cr = (lane >> 4)*4;
    float linv[4][4];
#pragma unroll
    for (int mt = 0; mt < 4; ++mt)
#pragma unroll
      for (int i = 0; i < 4; ++i)
        linv[mt][i] = 1.f / rs[(long long)z*sRs + (m0 + wm*64 + mt*16 + cr + i)];
    float s2[TNW];
#pragma unroll
    for (int nt = 0; nt < TNW; ++nt) {
      s2[nt] = 0.f;
#pragma unroll
      for (int mt = 0; mt < 4; ++mt)
#pragma unroll
        for (int i = 0; i < 4; ++i) {
          float v = acc[mt][nt][i] * linv[mt][i];
          s2[nt] += v*v;
        }
      s2[nt] += __shfl_xor(s2[nt], 16, 64);
      s2[nt] += __shfl_xor(s2[nt], 32, 64);
    }
    __syncthreads();   // protect redcs reads above before lA-alias writes
    if (lane < 16) {
#pragma unroll
      for (int nt = 0; nt < TNW; ++nt)
        red2[(wvi*TNW + nt)*16 + lane] = s2[nt];
    }
    __syncthreads();
    if (tid < TN) {
      const int wn2 = tid / (TNW*16), rem = tid % (TNW*16);
      float v = red2[wn2*(TNW*16) + rem] + red2[(2+wn2)*(TNW*16) + rem];
      atomicAdd(&osum2[sCb*z + n0 + tid], v);
    }
    return;
  }

  const int cr = (lane >> 4)*4, cc = lane & 15;
#pragma unroll
  for (int mt = 0; mt < 4; ++mt) {
#pragma unroll
    for (int i = 0; i < 4; ++i) {
      const int mm = m0 + wm*64 + mt*16 + cr + i;
      float rsum = 0.f, rsum2 = 0.f;
#pragma unroll
      for (int nt = 0; nt < TNW; ++nt) {
        const int nn = n0 + wn*(TNW*16) + nt*16 + cc;
        float v = acc[mt][nt][i];
        const long long co = sC*z + (long long)mm*ldc + nn;
        if (EPI == 0) {
          v *= scale;
          if (cbias) v += cbias[sCb*z + nn];
          ((bf16*)Cout)[co] = f2b(v);
        } else if (EPI == 2) {
          v = fmaxf(v*rs[mm] + rsh[mm], 0.f);
          ((float*)Cout)[co] = v;
          rsum += v; rsum2 += v*v;
        } else if (EPI == 4) {
          v = __expf(v);
          ((bf16*)Cout)[co] = f2b(v);
          rsum += v;
        } else if (EPI == 5) {
          v = v*rs[(long long)z*sRs + mm] + rsh[(long long)z*sRs + mm]*cbias[sCb*z + nn];
          ((bf16*)Cout)[co] = f2b(v);
        }
      }
      if (EPI == 2 || EPI == 4) {
        // reduce across the 16 cc lanes (row constant there)
        rsum += __shfl_xor(rsum, 1, 64); rsum += __shfl_xor(rsum, 2, 64);
        rsum += __shfl_xor(rsum, 4, 64); rsum += __shfl_xor(rsum, 8, 64);
        if (EPI == 2) {
          rsum2 += __shfl_xor(rsum2, 1, 64); rsum2 += __shfl_xor(rsum2, 2, 64);
          rsum2 += __shfl_xor(rsum2, 4, 64); rsum2 += __shfl_xor(rsum2, 8, 64);
        }
        if (cc == 0) {
          atomicAdd(&osum[(long long)z*sRs + mm], rsum);
          if (EPI == 2) atomicAdd(&osum2[(long long)z*sRs + mm], rsum2);
        }
      }
    }
  }
}

// ---------------------------------------------------------------------------
// QK->exp specialized GEMM (r7-proven): 256x256 tile, BK=64, 512 threads
// (8 waves, 2x4), double-buffered LDS, counted vmcnt(8) (never drained in
// main loop — r8 showed drain-to-0 single-buffer costs ~7% with NO occupancy
// gain), per-phase raw s_barrier + s_setprio around each 16-MFMA cluster.
// XCD-chunked swizzle (r5: FETCH 79->24.7 MB). Epilogue: exp + row-sum
// atomics staged through dead LDS ([256][264] bf16) then full-line copy-out.
// C[m,n] = exp(sum_k Q[m,k]*K[n,k]) bf16 + per-row sum atomics into lsum.
// QK slab layout: slab = side*8 + b*2 + ph; z = ph*4 + b.
// Shapes hardcoded: M=N=2048, K=512, ld=512, ldc=2048.
// ---------------------------------------------------------------------------
__global__ void __launch_bounds__(512, 2) qk_exp_k(
    const bf16* __restrict__ QK, bf16* __restrict__ P, float* __restrict__ lsum)
{
  // buffer b: A tile [256][64] bf16 at b*65536 bytes, B tile at +32768 bytes.
  // physical chunk c of row r holds logical k-chunk c ^ (r&7)  (16B chunks)
  // epilogue reuses lds as padded C tile [256][264] bf16 = 135168 B.
  __shared__ alignas(16) char lds[135168];
  const int tid = threadIdx.x;
  const int bid = blockIdx.x;
  const int xcd = bid & 7, slot = bid >> 3;
  const int z  = (xcd >> 1) + ((slot >> 5) << 2);
  const int t  = (slot & 31) + ((xcd & 1) << 5);
  const int by = t >> 3, bx = t & 7;
  const int ph = z >> 2, b = z & 3;
  const bf16* Qb = QK + (long long)(b*2 + ph) * (2048LL*512);
  const bf16* Kb = QK + (long long)(8 + b*2 + ph) * (2048LL*512);
  const int m0 = by * 256, n0 = bx * 256;
  const int lane = tid & 63, wvi = tid >> 6;
  const int wm = wvi >> 2, wn = wvi & 3;          // 2 x 4 wave grid
  const int l15 = lane & 15, lq = lane >> 4;
  const int swz = l15 & 7;

  f32x4 acc[8][4] = {};

  // loader: 512 threads x 16B = 8KB/issue = 64 rows of 64 bf16; 4 issues/tile.
  // global source pre-swizzled so the linear LDS write lands swizzled (m173).
  const int lr = tid >> 3;
  const int lc = ((tid ^ lr) & 7) * 8;
  const bf16* pa = Qb + (long long)(m0 + lr)*512 + lc;
  const bf16* pb = Kb + (long long)(n0 + lr)*512 + lc;

  auto STAGE = [&](int bb, int kt) {
    char* da = (char*)lds + bb*65536 + tid*16;
    const bf16* ga = pa + kt*64;
    const bf16* gb = pb + kt*64;
#pragma unroll
    for (int it = 0; it < 4; ++it) gl_lds16(ga + it*64*512, da + it*8192);
#pragma unroll
    for (int it = 0; it < 4; ++it) gl_lds16(gb + it*64*512, da + 32768 + it*8192);
  };

  STAGE(0, 0);
  for (int kt = 0; kt < 8; ++kt) {
    const int cur = kt & 1;
    if (kt < 7) {
      STAGE(cur ^ 1, kt + 1);                      // 8 new loads in flight
      asm volatile("s_waitcnt vmcnt(8)" ::: "memory");   // wait only kt's 8
    } else {
      asm volatile("s_waitcnt vmcnt(0)" ::: "memory");
    }
    __builtin_amdgcn_s_barrier();                  // buf[cur] visible to all

    const bf16* lA = (const bf16*)(lds + cur*65536);
    const bf16* lB = lA + 16384;

    bf16x8 af[4], bfr[4];
    // 4 phases per K-tile: {ks0,m0-3} {ks0,m4-7} {ks1,m0-3} {ks1,m4-7}
#pragma unroll
    for (int half = 0; half < 4; ++half) {
      const int ks = half >> 1, mg = (half & 1) * 4;
      const int kq = ks*4 + lq;
      const int ko = (kq ^ swz) * 8;
      if ((half & 1) == 0) {
#pragma unroll
        for (int nt = 0; nt < 4; ++nt)
          bfr[nt] = *(const bf16x8*)&lB[(wn*64 + nt*16 + l15)*64 + ko];
      }
#pragma unroll
      for (int mt = 0; mt < 4; ++mt)
        af[mt] = *(const bf16x8*)&lA[(wm*128 + (mg + mt)*16 + l15)*64 + ko];
      __builtin_amdgcn_s_barrier();
      __builtin_amdgcn_s_setprio(1);
#pragma unroll
      for (int mt = 0; mt < 4; ++mt)
#pragma unroll
        for (int nt = 0; nt < 4; ++nt)
          acc[mg + mt][nt] = __builtin_amdgcn_mfma_f32_16x16x32_bf16(
              af[mt], bfr[nt], acc[mg + mt][nt], 0, 0, 0);
      __builtin_amdgcn_s_setprio(0);
      __builtin_amdgcn_s_barrier();
    }
  }

  // ---- epilogue (no max-sub: logits ~ N(0,1)) ------------------------------
  // Phase 1: exp + per-row sums into LDS-staged padded C tile.
  constexpr int LDC = 264;                         // bf16 row stride (528 B)
  bf16* lC = (bf16*)lds;                           // buffers dead after barrier
  const long long zT = (long long)z * 2048;
  float* lrw = lsum + zT;
  const int cr = lq * 4;
#pragma unroll
  for (int mt = 0; mt < 8; ++mt) {
#pragma unroll
    for (int i = 0; i < 4; ++i) {
      const int mmL = wm*128 + mt*16 + cr + i;
      float rsum = 0.f;
#pragma unroll
      for (int nt = 0; nt < 4; ++nt) {
        const int nnL = wn*64 + nt*16 + l15;
        float v = __expf(acc[mt][nt][i]);
        lC[mmL*LDC + nnL] = f2b(v);
        rsum += v;
      }
      rsum += __shfl_xor(rsum, 1, 64); rsum += __shfl_xor(rsum, 2, 64);
      rsum += __shfl_xor(rsum, 4, 64); rsum += __shfl_xor(rsum, 8, 64);
      if (l15 == 0) atomicAdd(&lrw[m0 + mmL], rsum);
    }
  }
  __syncthreads();
  // Phase 2: coalesced copy-out, 16B/thread/iter; 32 lanes = 512B contiguous.
  bf16* Cb = P + zT * 2048;
#pragma unroll
  for (int j = 0; j < 16; ++j) {
    const int flat = j*512 + tid;                  // 16B-chunk id in [0,8192)
    const int r = flat >> 5, c16 = flat & 31;
    const f32x4 v = *(const f32x4*)&lC[r*LDC + c16*8];
    *(f32x4*)&Cb[(long long)(m0 + r)*2048 + n0 + c16*8] = v;
  }
}

// ---------------------------------------------------------------------------
// Fused transpose + stats: reads src/trg f32 ONCE (replaces row_stats_k +
// col_stats_k + transform_k, 3x33.5MB reads -> 1x). Per (z, t0:32, c0:64)
// block: stage f32 tile in LDS, write XT bf16 in full 128B lines, reduce
// row (per z,c over t) and col (per z,t over c) sum/sumsq partials in LDS,
// atomically accumulate into rsum/rsum2/csum/csum2 (zeroed beforehand).
// ---------------------------------------------------------------------------
__global__ void __launch_bounds__(256) transform_stats_k(
    const float* __restrict__ src, const float* __restrict__ trg,
    bf16* __restrict__ XT, float* __restrict__ rsum, float* __restrict__ rsum2,
    float* __restrict__ csum, float* __restrict__ csum2)
{
  __shared__ float tile[64][33];
  __shared__ float rp1[64][4], rp2[64][4];
  __shared__ float cp1[32][8], cp2[32][8];
  const int z = blockIdx.z, t0 = blockIdx.x*32, c0 = blockIdx.y*64;
  const int is_t = z >= B_, b = z & (B_-1);
  const float* X = is_t ? trg : src;
  const int tid = threadIdx.x;
  const int tx = tid & 31, cy = tid >> 5;          // t lane, c group (8)
#pragma unroll
  for (int it = 0; it < 8; ++it) {
    const int cl = cy + it*8;
    tile[cl][tx] = X[((long long)b*C_ + c0 + cl)*T_ + t0 + tx];
  }
  __syncthreads();
  // XT write: lane packs 2 bf16 -> 4B; 32 lanes = 128B full line per t-row.
  const int l32 = tid & 31, tq = tid >> 5;
#pragma unroll
  for (int r = 0; r < 4; ++r) {
    const int tl = r*8 + tq;
    bf16 b0 = f2b(tile[2*l32][tl]), b1 = f2b(tile[2*l32+1][tl]);
    unsigned short u0, u1;
    __builtin_memcpy(&u0, &b0, 2); __builtin_memcpy(&u1, &b1, 2);
    const unsigned int pk = (unsigned int)u0 | ((unsigned int)u1 << 16);
    *(unsigned int*)&XT[((long long)z*T_ + t0 + tl)*C_ + c0 + 2*l32] = pk;
  }
  // row partials: thread (cl = tid>>2, g = tid&3) sums t = g+4k, k<8
  {
    const int cl = tid >> 2, g = tid & 3;
    float s1 = 0.f, s2 = 0.f;
#pragma unroll
    for (int k = 0; k < 8; ++k){ float v = tile[cl][g + 4*k]; s1 += v; s2 += v*v; }
    rp1[cl][g] = s1; rp2[cl][g] = s2;
  }
  // col partials: thread (tl = tid>>3, g = tid&7) sums c = g+8k, k<8
  {
    const int tl = tid >> 3, g = tid & 7;
    float s1 = 0.f, s2 = 0.f;
#pragma unroll
    for (int k = 0; k < 8; ++k){ float v = tile[g + 8*k][tl]; s1 += v; s2 += v*v; }
    cp1[tl][g] = s1; cp2[tl][g] = s2;
  }
  __syncthreads();
  if (tid < 64) {
    float s1 = rp1[tid][0]+rp1[tid][1]+rp1[tid][2]+rp1[tid][3];
    float s2 = rp2[tid][0]+rp2[tid][1]+rp2[tid][2]+rp2[tid][3];
    atomicAdd(&rsum[z*C_ + c0 + tid], s1);
    atomicAdd(&rsum2[z*C_ + c0 + tid], s2);
  } else if (tid < 96) {
    const int tl = tid - 64;
    float s1 = 0.f, s2 = 0.f;
#pragma unroll
    for (int g = 0; g < 8; ++g){ s1 += cp1[tl][g]; s2 += cp2[tl][g]; }
    atomicAdd(&csum[z*T_ + t0 + tl], s1);
    atomicAdd(&csum2[z*T_ + t0 + tl], s2);
  }
}

// ---- finalize both stat axes (ddof=1): rows (z,c) then cols (z,t) ----------
__global__ void __launch_bounds__(256) statfin_k(
    const float* __restrict__ rsum, const float* __restrict__ rsum2,
    const float* __restrict__ csum, const float* __restrict__ csum2,
    float* __restrict__ inm, float* __restrict__ ins,
    float* __restrict__ tnm, float* __restrict__ tns)
{
  const int i = blockIdx.x*256 + threadIdx.x;   // 80 blocks = 20480
  if (i < 2*B_*C_) {
    const float s1 = rsum[i], s2 = rsum2[i];
    const float m = s1 * (1.f/T_);
    const float var = (s2 - s1*m) * (1.f/(T_-1));
    inm[i] = m; ins[i] = sqrtf(fmaxf(var, 0.f));
  } else {
    const int j = i - 2*B_*C_;
    const float s1 = csum[j], s2 = csum2[j];
    const float m = s1 * (1.f/C_);
    const float var = (s2 - s1*m) * (1.f/(C_-1));
    tnm[j] = m; tns[j] = sqrtf(fmaxf(var, 0.f));
  }
}

// ---- fold norm into QK projection weights + biases -------------------------
// W[z][o][c], cb[z][o]; z = side*8 + b*2 + ph (side 0=Q/src, 1=K/trg)
// ph0 (CAN/inorm): W = w*sc/(is+eps), cb = -sum_c W*im   (epilogue rs=rsh=1)
// ph1 (TAN/tinorm): W = w*sc,         cb = sum_c W       (row-affine epi)
__global__ void __launch_bounds__(256) foldqk_k(
    const float* __restrict__ wq_c, const float* __restrict__ wq_t,
    const float* __restrict__ wk_c, const float* __restrict__ wk_t,
    const float* __restrict__ inm, const float* __restrict__ ins,
    bf16* __restrict__ W, float* __restrict__ cb)
{
  __shared__ float r1[4];
  const int o = blockIdx.x, z = blockIdx.y;
  const int side = z >> 3, b = (z >> 1) & 3, ph = z & 1;
  const float* w = side ? (ph ? wk_t : wk_c) : (ph ? wq_t : wq_c);
  const float sc = side ? 1.f : 0.044194173824159216f;   // 1/sqrt(C) on Q
  const int ofs = (side*B_ + b)*C_;
  float acc = 0.f;
  for (int c = threadIdx.x; c < C_; c += 256) {
    float wv = w[o*C_ + c] * sc;
    float out, contrib;
    if (ph == 0) {
      float ri = 1.f / (ins[ofs + c] + EPSF);
      out = wv * ri;
      contrib = -out * inm[ofs + c];
    } else {
      out = wv;
      contrib = wv;
    }
    W[((long long)z*C_ + o)*C_ + c] = f2b(out);
    acc += contrib;
  }
  acc = wave_sum(acc);
  const int lane = threadIdx.x & 63, wq = threadIdx.x >> 6;
  if (!lane) r1[wq] = acc;
  __syncthreads();
  if (threadIdx.x == 0) cb[z*C_ + o] = r1[0]+r1[1]+r1[2]+r1[3];
}

// ---- per-z row scale/shift for EPI 5 ---------------------------------------
__global__ void __launch_bounds__(256) rsfill_k(
    const float* __restrict__ tnm, const float* __restrict__ tns,
    float* __restrict__ rsq, float* __restrict__ rshq)
{
  const int z = blockIdx.y, t = blockIdx.x*256 + threadIdx.x;  // grid (8,16)
  const int side = z >> 3, b = (z >> 1) & 3, ph = z & 1;
  float rv, rh;
  if (ph == 0) { rv = 1.f; rh = 1.f; }
  else {
    const int ofs = (side*B_ + b)*T_;
    float r = 1.f / (tns[ofs + t] + EPSF);
    rv = r; rh = -tnm[ofs + t] * r;
  }
  rsq[z*T_ + t] = rv; rshq[z*T_ + t] = rh;
}

// ---- vv-GEMV: meanc = (1/S) sum_t cs[t]*V[c,t]  (colsum identity),
//      stdc from m2sum + sum_t cs[t]*V^2; z in [0,2B) ------------------------
__global__ void __launch_bounds__(256) vv_fin_k(const float* __restrict__ cs,
    const bf16* __restrict__ VT,
    const float* __restrict__ m2sum, float* __restrict__ meanc, float* __restrict__ stdc)
{
  __shared__ float r1[4], r2[4];
  const int c = blockIdx.x, z = blockIdx.y;
  const bf16* vr = VT + ((long long)z*C_ + c)*T_;
  const float* w = cs + z*T_;
  float a1 = 0.f, a2 = 0.f;
  for (int t = threadIdx.x; t < T_; t += 256){
    float v = b2f(vr[t]); float wt = w[t];
    a1 += wt*v; a2 += wt*v*v;
  }
  a1 = wave_sum(a1); a2 = wave_sum(a2);
  const int lane = threadIdx.x & 63, wq = threadIdx.x >> 6;
  if (!lane){ r1[wq] = a1; r2[wq] = a2; }
  __syncthreads();
  if (threadIdx.x == 0){
    a1 = r1[0]+r1[1]+r1[2]+r1[3];
    a2 = r2[0]+r2[1]+r2[2]+r2[3];
    const int idx = z*C_ + c;
    meanc[idx] = a1 * (1.f/S_);
    float var = (a2 - m2sum[idx]) * (1.f/S_);
    stdc[idx] = sqrtf(fmaxf(var, 0.f));
  }
}

// ---- fold adaptive-norm epilogue + concat + inorm(src) into conv1 weights --
__global__ void __launch_bounds__(256) weff_k(const float* __restrict__ w1,
    const float* __restrict__ b1, const float* __restrict__ sdt, const float* __restrict__ sdc,
    const float* __restrict__ mct, const float* __restrict__ mcc,
    const float* __restrict__ inm, const float* __restrict__ ins,
    bf16* __restrict__ Weff, float* __restrict__ beff)
{
  __shared__ float r1[4];
  const int o = blockIdx.x, b = blockIdx.y;
  const int ofs = b*C_;                       // src inorm slab
  float accb = 0.f;
  for (int c = threadIdx.x; c < C_; c += 256) {
    float wa = w1[o*2*C_ + c], wb = w1[o*2*C_ + C_ + c];
    float s = wa*sdt[b*C_+c] + wb*sdc[b*C_+c];
    float w2 = s / (ins[ofs + c] + EPSF);
    Weff[((long long)(b*C_ + o))*C_ + c] = f2b(w2);
    accb += wa*mct[b*C_+c] + wb*mcc[b*C_+c] - w2*inm[ofs + c];
  }
  accb = wave_sum(accb);
  const int lane = threadIdx.x & 63, w = threadIdx.x >> 6;
  if (!lane) r1[w] = accb;
  __syncthreads();
  if (threadIdx.x == 0) beff[b*C_ + o] = b1[o] + r1[0]+r1[1]+r1[2]+r1[3];
}

// ---- conv2 weight reorder (k = dt*C + c) + BN scale/shift ------------------
__global__ void __launch_bounds__(256) w2r_k(const float* __restrict__ w2,
    const float* __restrict__ g, const float* __restrict__ be,
    const float* __restrict__ mu, const float* __restrict__ va,
    bf16* __restrict__ W2r, float* __restrict__ bnsc, float* __restrict__ bnsh)
{
  const int o = blockIdx.x;
  for (int c = threadIdx.x; c < C_; c += 256)
#pragma unroll
    for (int dt = 0; dt < 3; ++dt)
      W2r[(long long)o*3*C_ + dt*C_ + c] = f2b(w2[((long long)o*C_ + c)*3 + dt]);
  if (threadIdx.x == 0) {
    float s = g[o] * rsqrtf(va[o] + EPSF);
    bnsc[o] = s;
    bnsh[o] = be[o] - mu[o]*s;
  }
}

// ---- cast wv_c, wv_t to bf16 -----------------------------------------------
__global__ void __launch_bounds__(256) castv_k(const float* __restrict__ a0,
    const float* __restrict__ a1, bf16* __restrict__ o)
{
  const int i = blockIdx.x*256 + threadIdx.x;   // 2*262144
  o[i] = f2b(((i >> 18) ? a1 : a0)[i & 262143]);
}

// ---- zero pad rows of x1p --------------------------------------------------
__global__ void __launch_bounds__(256) zero_pad_k(bf16* __restrict__ x1p)
{
  const int i = blockIdx.x*256 + threadIdx.x;   // 4096
  const int b = i >> 10, rem = i & 1023;
  const long long row = (rem >> 9) ? (T_+1) : 0;
  const int c = rem & (C_-1);
  x1p[((long long)b*(T_+2) + row)*C_ + c] = f2b(0.f);
}

__global__ void __launch_bounds__(256) zero_f32_k(float* __restrict__ p)
{
  p[blockIdx.x*256 + threadIdx.x] = 0.f;
}

// ---- SAP: unnormalized exp-logits e = exp(x.w + b); softmax normalization
//      commutes out of the weighted sum: sap = (sum_n e_n x_n)/(sum_n e_n).
//      Max-sub-free exp is safe (logit ~ N(0,~1), same argument as QK). -----
__global__ void __launch_bounds__(256) sap_logit_k(const float* __restrict__ means,
    const float* __restrict__ stds, const float* __restrict__ mw, const float* __restrict__ sw,
    const float* __restrict__ mb, const float* __restrict__ sb, float* __restrict__ out)
{
  const int n = blockIdx.x*4 + (threadIdx.x >> 6);
  const int z = blockIdx.y;
  const int sel = z >= B_, b = z & (B_-1);
  const float* x = sel ? stds : means;
  const float* w = sel ? sw : mw;
  const int lane = threadIdx.x & 63;
  const float* p = x + ((long long)b*S_ + n)*C_;
  float a = 0.f;
  for (int c = lane; c < C_; c += 64) a += p[c]*w[c];
  a = wave_sum(a);
  if (!lane) out[z*S_ + n] = __expf(a + (sel ? sb[0] : mb[0]));
}

// ---- SAP: unnormalized weighted sum over n (chunked, atomic), z in [0,2B);
//      c-chunk-0 blocks also accumulate per-z exp-sum into esum -------------
__global__ void __launch_bounds__(256) sap_wsum_k(const float* __restrict__ means,
    const float* __restrict__ stds, const float* __restrict__ a, float* __restrict__ out,
    float* __restrict__ esum)
{
  __shared__ float r1[4];
  const int c = blockIdx.x*256 + threadIdx.x;
  const int z = blockIdx.z;
  const int sel = z >= B_, b = z & (B_-1);
  const float* x = sel ? stds : means;
  const long long n0 = (long long)blockIdx.y*256;
  const float* p = x + ((long long)b*S_ + n0)*C_ + c;
  const float* aw = a + z*S_ + n0;
  float acc = 0.f;
  for (int n = 0; n < 256; ++n) acc += p[(long long)n*C_] * aw[n];
  atomicAdd(&out[z*C_ + c], acc);
  if (blockIdx.x == 0) {
    float e = wave_sum(aw[threadIdx.x]);
    const int lane = threadIdx.x & 63, w = threadIdx.x >> 6;
    if (!lane) r1[w] = e;
    __syncthreads();
    if (threadIdx.x == 0) atomicAdd(&esum[z], r1[0]+r1[1]+r1[2]+r1[3]);
  }
}

// ---- final: inorm(y)*sap_std + sap_mean; sap sums normalized by esum here --
__global__ void __launch_bounds__(256) final_k(const float* __restrict__ y,
    const float* __restrict__ ysum, const float* __restrict__ y2sum,
    const float* __restrict__ sapms, const float* __restrict__ esum,
    float* __restrict__ out)
{
  const long long i = (long long)(blockIdx.x*256 + threadIdx.x) * 4;
  const long long r = i >> 11;
  const int b = (int)(r >> 9);                  // C_ = 512
  const float s1 = ysum[r], s2 = y2sum[r];
  const float m = s1 * (1.f/T_);
  const float var = (s2 - s1*m) * (1.f/(T_-1));
  const float inv = 1.f/(sqrtf(fmaxf(var, 0.f)) + EPSF);
  const float mn = sapms[r] / esum[b];
  const float sd = sapms[B_*C_ + r] / esum[B_ + b];
  const f32x4 v = *(const f32x4*)(y + i);
  f32x4 o;
#pragma unroll
  for (int j = 0; j < 4; ++j) o[j] = (v[j] - m)*inv*sd + mn;
  *(f32x4*)(out + i) = o;
}

// ---------------------------------------------------------------------------
extern "C" void kernel_launch(void* const* d_in, const int* in_sizes, int n_in,
                              void* d_out, int out_size, void* d_ws, size_t ws_size,
                              hipStream_t stream)
{
  (void)in_sizes; (void)n_in; (void)out_size; (void)ws_size;
  const float* src    = (const float*)d_in[0];
  const float* trg    = (const float*)d_in[1];
  const float* means  = (const float*)d_in[2];
  const float* stds   = (const float*)d_in[3];
  const float* conv1w = (const float*)d_in[10];
  const float* conv1b = (const float*)d_in[11];
  const float* conv2w = (const float*)d_in[12];
  const float* bn_g   = (const float*)d_in[13];
  const float* bn_b   = (const float*)d_in[14];
  const float* bn_m   = (const float*)d_in[15];
  const float* bn_v   = (const float*)d_in[16];
  const float* msap_w = (const float*)d_in[17];
  const float* msap_b = (const float*)d_in[18];
  const float* ssap_w = (const float*)d_in[19];
  const float* ssap_b = (const float*)d_in[20];

  const long long BTC = (long long)B_*T_*C_;   // 4194304 elems
  const long long TC  = (long long)T_*C_;      // 1048576 elems

  char* p = (char*)d_ws;
  auto take = [&](size_t n)->char*{ char* r = p; p += (n + 255) & ~(size_t)255; return r; };

  // Phase convention: p=0 -> CAN (inorm), p=1 -> TAN (tinorm); z = p*B + b.
  bf16* P2  = (bf16*)take((size_t)2*B_*S_*T_*2);           // 64 MB (exp logits)
  bf16* QK4 = (bf16*)take((size_t)16*TC*2);                // 32 MB (16 slabs)
  bf16* VT2 = (bf16*)take((size_t)2*BTC*2);                // 16 MB [2][B][C][T]
  bf16* WQeff = (bf16*)take((size_t)16*C_*C_*2);           // 8 MB folded wq/wk
  bf16* WVb = (bf16*)take((size_t)2*C_*C_*2);              // 1 MB wv bf16
  bf16* Weff= (bf16*)take((size_t)B_*C_*C_*2);
  bf16* W2r = (bf16*)take((size_t)C_*3*C_*2);
  bf16* x1p = (bf16*)take((size_t)B_*(T_+2)*C_*2);
  float* y  = (float*)take((size_t)B_*C_*T_*4);            // 16 MB
  bf16* XT  = (bf16*)y;   // alias: XT (raw transposes, 16 MB) dead before
                          // conv2 writes y; lifetimes are stream-disjoint.
  // contiguous zero block: colsum..csum2 (90112 elems) + esum pad (64) =
  // 90176 -> 353 zero_f32_k blocks (192-elem overrun lands in tnm, which
  // statfin_k fully overwrites later; ordering-safe).
  float* colsum = (float*)take(2*B_*T_*4);                 // 16384 elems
  float* msum   = (float*)take(2*B_*C_*4);                 // 4096 (unused now)
  float* m2sum  = (float*)take(2*B_*C_*4);                 // 4096
  float* sapms  = (float*)take(2*B_*C_*4);                 // 4096
  float* lrow   = (float*)take(2*B_*S_*4);                 // 16384
  float* ysum   = (float*)take(B_*C_*4);                   // 2048
  float* y2sum  = (float*)take(B_*C_*4);                   // 2048
  float* rsum   = (float*)take(2*B_*C_*4);                 // 4096
  float* rsum2  = (float*)take(2*B_*C_*4);                 // 4096
  float* csum   = (float*)take(2*B_*T_*4);                 // 16384
  float* csum2  = (float*)take(2*B_*T_*4);                 // 16384 => 90112
  float* esum   = (float*)take(2*B_*4);                    // 8 (pad 64)
  float* tnm = (float*)take(2*B_*T_*4);
  float* tns = (float*)take(2*B_*T_*4);
  float* inm = (float*)take(2*B_*C_*4);
  float* ins = (float*)take(2*B_*C_*4);
  float* meanc = (float*)take(2*B_*C_*4);                  // [2][B][C]
  float* stdc  = (float*)take(2*B_*C_*4);
  float* beff  = (float*)take(B_*C_*4);
  float* bnsc  = (float*)take(C_*4);
  float* bnsh  = (float*)take(C_*4);
  float* sapl  = (float*)take(2*B_*S_*4);                  // unnormalized e
  float* cbq   = (float*)take(16*C_*4);                    // folded biases
  float* rsq   = (float*)take(16*T_*4);                    // row scales
  float* rshq  = (float*)take(16*T_*4);                    // row shifts
  (void)msum;

  dim3 blk(256);

  zero_f32_k<<<353, blk, 0, stream>>>(colsum);    // colsum..esum (+overrun)
  castv_k<<<2048, blk, 0, stream>>>((const float*)d_in[9], (const float*)d_in[6], WVb);
  w2r_k<<<C_, blk, 0, stream>>>(conv2w, bn_g, bn_b, bn_m, bn_v, W2r, bnsc, bnsh);
  // fused transpose + both stat axes (single pass over src/trg)
  transform_stats_k<<<dim3(T_/32, C_/64, 2*B_), blk, 0, stream>>>(src, trg, XT,
      rsum, rsum2, csum, csum2);
  statfin_k<<<80, blk, 0, stream>>>(rsum, rsum2, csum, csum2, inm, ins, tnm, tns);
  foldqk_k<<<dim3(C_, 16), blk, 0, stream>>>((const float*)d_in[7], (const float*)d_in[4],
      (const float*)d_in[8], (const float*)d_in[5], inm, ins, WQeff, cbq);
  rsfill_k<<<dim3(T_/256, 16), blk, 0, stream>>>(tnm, tns, rsq, rshq);
  zero_pad_k<<<16, blk, 0, stream>>>(x1p);

  // QKV projections on RAW transposed panels with norm-fold epilogue (EPI 5).
  // z in [0,16): A = XT slab z/2 (src b0..3, trg b0..3), B/epi slab z.
  // XCD-chunked: xcd owns z = {2*xcd, 2*xcd+1} -> shared XT slab L2-resident.
  gemm_nt<5,4,4,16,16><<<dim3(1024), blk, 0, stream>>>(XT, WQeff, QK4,
      C_, C_, C_, C_, TC, (long long)C_*C_, TC, C_,
      2, 16, 1.f, rsq, rshq, cbq, nullptr, nullptr, T_, nullptr);
  // V^T[z] = wv[p] @ trg[b]^T -> [C,T]; z in [0,8): p=z/4, b=z%4
  // XCD-chunked: xcd = z -> trg XT slab + weight slab L2-resident.
  gemm_nt<0,2,32,4,8><<<dim3(1024), blk, 0, stream>>>(WVb, XT + 4*TC, VT2,
      C_, C_, C_, T_, (long long)C_*C_, TC, (long long)C_*T_, 0, 4, 4, 1.f,
      nullptr, nullptr, nullptr, nullptr, nullptr, 0, nullptr);
  // P' = exp(Q @ K^T) bf16 + row sums l (no max-sub: logits ~ N(0,1))
  // 256^2-tile 8-wave double-buffered pipeline (counted vmcnt), XCD-chunked
  qk_exp_k<<<dim3(512), dim3(512), 0, stream>>>(QK4, P2, lrow);
  // PV with fused (1/l)-scaled sum_s^2 epilogue (m2sum; no output store)
  // + fused colsum of P'/l over s into colsum (mean path via identity)
  // XCD-chunked: xcd = z -> P panels read once into L2, 4 c-blocks hit.
  gemm_nt<3,4,4,16,8><<<dim3(512), blk, 0, stream>>>(P2, VT2, nullptr,
      T_, T_, T_, 0, (long long)S_*T_, (long long)C_*T_, 0, C_, 1, 8, 1.f,
      lrow, nullptr, nullptr, nullptr, m2sum, S_, colsum);
  vv_fin_k<<<dim3(C_, 2*B_), blk, 0, stream>>>(colsum, VT2, m2sum, meanc, stdc);

  // conv1 folded with adaptive-norm + inorm(src) epilogues on raw XT
  weff_k<<<dim3(C_, B_), blk, 0, stream>>>(conv1w, conv1b,
      stdc + B_*C_, stdc, meanc + B_*C_, meanc, inm, ins, Weff, beff);
  // XCD-chunked: xcd pair shares z -> src XT slab + Weff slab L2-resident.
  gemm_nt<0,2,8,16,4><<<dim3(512), blk, 0, stream>>>(XT, Weff, x1p + C_,
      C_, C_, C_, C_, TC, (long long)C_*C_, (long long)(T_+2)*C_, C_,
      1, 8, 1.f, nullptr, nullptr, beff, nullptr, nullptr, 0, nullptr);
  // conv2 (k=3) as overlapping-row NT GEMM + BN+ReLU + fused row-stat sums
  gemm_nt<2,2,32,4,4><<<dim3(512), blk, 0, stream>>>(W2r, x1p, y,
      3*C_, 3*C_, C_, T_, 0, (long long)(T_+2)*C_, (long long)C_*T_, 0,
      1, 8, 1.f, bnsc, bnsh, nullptr, ysum, y2sum, C_, nullptr);

  // SAP: unnormalized exp weights; normalization deferred to final_k
  sap_logit_k<<<dim3(S_/4, 2*B_), blk, 0, stream>>>(means, stds, msap_w, ssap_w,
      msap_b, ssap_b, sapl);
  sap_wsum_k<<<dim3(C_/256, S_/256, 2*B_), blk, 0, stream>>>(means, stds, sapl,
      sapms, esum);

  final_k<<<4096, blk, 0, stream>>>(y, ysum, y2sum, sapms, esum, (float*)d_out);
}

// Round 11
// 396.110 us; speedup vs baseline: 1.0189x; 1.0189x over previous
//
#include <hip/hip_runtime.h>
#include <cstdint>
#include <cstddef>

#define B_ 4
#define C_ 512
#define T_ 2048
#define S_ 2048
#define EPSF 1e-5f

typedef __bf16 bf16;
typedef __attribute__((ext_vector_type(8))) __bf16 bf16x8;
typedef __attribute__((ext_vector_type(4))) float f32x4;

__device__ __forceinline__ bf16 f2b(float f){ return (bf16)f; }
__device__ __forceinline__ float b2f(bf16 h){ return (float)h; }

__device__ __forceinline__ void gl_lds16(const void* g, void* l){
  __builtin_amdgcn_global_load_lds((__attribute__((address_space(1))) void*)(g),
                                   (__attribute__((address_space(3))) void*)(l), 16, 0, 0);
}

__device__ __forceinline__ float wave_sum(float v){
#pragma unroll
  for (int o = 32; o; o >>= 1) v += __shfl_xor(v, o, 64);
  return v;
}
__device__ __forceinline__ float wave_max(float v){
#pragma unroll
  for (int o = 32; o; o >>= 1) v = fmaxf(v, __shfl_xor(v, o, 64));
  return v;
}

// ---------------------------------------------------------------------------
// NT GEMM: C[m,n] = sum_k A[m,k]*B[n,k], both operands k-contiguous (bf16),
// fp32 MFMA accum. Tile 128 x (TNW*32), BK=64, 256 threads (2x2 waves).
// z-batched: A offset (z/zdivA)*sA, B offset (z%zmodB)*sB, C offset z*sC.
// GX/GY/NZ > 0: launched as flat 1D grid of GX*GY*NZ blocks with XCD-chunked
// decode — xcd=bid&7 owns a fixed z-slab subset so same-z blocks co-reside
// on one XCD and their shared A/B panels stay L2-hot (r5-verified: qk FETCH
// 79->24.7 MB). Bijective remap; no numerics change.
// EPI 0: bf16 store (acc*scale + cbias[n])
// EPI 2: f32 store relu(acc*rs[m%?]+rsh[..]) + fused per-row sum/sum^2 atomics
// EPI 3: no store — per-column sum^2 over m of acc*rlinv[row] (rlinv=1/l)
//        into osum2 only (mean-sum comes from colsum identity in vv_fin)
//        + fused colsum: ocol[t] += sum_s lA[s,t]*rlinv[s] for owned K-steps
//        (block bx owns K-steps with (k0/64)%4 == bx; exact 1x coverage)
// EPI 4: bf16 store exp(acc) + per-row partial-sum atomics into osum (l)
// EPI 5: bf16 store acc*rs[z,m] + rsh[z,m]*cbias[z,n]  (norm-fold epilogue)
// ---------------------------------------------------------------------------
template<int EPI, int TNW, int GX = 0, int GY = 0, int NZ = 0>
__global__ void __launch_bounds__(256) gemm_nt(
    const bf16* __restrict__ A, const bf16* __restrict__ Bm, void* __restrict__ Cout,
    int K, int lda, int ldb, int ldc,
    long long sA, long long sB, long long sC, long long sCb,
    int zdivA, int zmodB, float scale,
    const float* __restrict__ rs, const float* __restrict__ rsh,
    const float* __restrict__ cbias,
    float* __restrict__ osum, float* __restrict__ osum2, long long sRs,
    float* __restrict__ ocol)
{
  constexpr int TN = TNW*32;
  __shared__ alignas(16) bf16 lA[128*64];
  __shared__ alignas(16) bf16 lB[TN*64];
  __shared__ float redcs[EPI == 3 ? 32*68 : 1];   // colsum scratch (padded)
  const int tid = threadIdx.x;

  int bxv, byv, z;
  if constexpr (GX > 0) {
    const int bid = blockIdx.x;
    const int xcd = bid & 7, slot = bid >> 3;
    constexpr int NB  = GX*GY;                    // blocks per z
    constexpr int ZPX = (NZ >= 8) ? NZ/8 : 1;     // z per xcd
    constexpr int XPZ = (NZ >= 8) ? 1 : 8/NZ;     // xcds per z
    z = (xcd / XPZ) * ZPX + ((ZPX > 1) ? slot / NB : 0);
    const int inner = (ZPX > 1) ? (slot % NB)
                                : (slot + (xcd % XPZ) * (NB / XPZ));
    bxv = inner % GX; byv = inner / GX;
  } else {
    bxv = blockIdx.x; byv = blockIdx.y; z = blockIdx.z;
  }

  const bf16* Ab = A + (long long)(z / zdivA) * sA;
  const bf16* Bb = Bm + (long long)(z % zmodB) * sB;
  const int m0 = byv*128, n0 = bxv*TN;
  const int lane = tid & 63, wvi = tid >> 6;
  const int wm = wvi >> 1, wn = wvi & 1;

  f32x4 acc[4][TNW] = {};

  // loader: thread stages one 16B chunk/iter; XOR-swizzle k-chunk by (row&7)
  const int lrow = tid >> 3;
  const int lcol = ((tid ^ lrow) & 7) * 8;
  const bf16* pa = Ab + (long long)(m0 + lrow)*lda + lcol;
  const bf16* pb = Bb + (long long)(n0 + lrow)*ldb + lcol;
  char* sa = (char*)lA + tid*16;
  char* sb = (char*)lB + tid*16;

  // colsum: thread (g = tid>>3, ph = tid&7) handles rows g*4..g*4+3, logical
  // k-chunk ph of the staged A-tile. Preload 1/l for its 4 rows.
  const int csg = tid >> 3, csph = tid & 7;
  float linv4[4];
  if (EPI == 3) {
#pragma unroll
    for (int rr = 0; rr < 4; ++rr)
      linv4[rr] = 1.f / rs[(long long)z*sRs + (m0 + csg*4 + rr)];
  }

  for (int k0 = 0; k0 < K; k0 += 64) {
#pragma unroll
    for (int it = 0; it < 4; ++it)
      gl_lds16(pa + (long long)it*32*lda + k0, sa + it*4096);
#pragma unroll
    for (int it = 0; it < TNW; ++it)
      gl_lds16(pb + (long long)it*32*ldb + k0, sb + it*4096);
    __syncthreads();
#pragma unroll
    for (int ks = 0; ks < 2; ++ks) {
      const int kq = ks*4 + (lane >> 4);
      bf16x8 af[4], bfr[TNW];
#pragma unroll
      for (int mt = 0; mt < 4; ++mt) {
        int r = wm*64 + mt*16 + (lane & 15);
        af[mt] = *(const bf16x8*)&lA[r*64 + ((kq ^ (r & 7))*8)];
      }
#pragma unroll
      for (int nt = 0; nt < TNW; ++nt) {
        int r = wn*(TNW*16) + nt*16 + (lane & 15);
        bfr[nt] = *(const bf16x8*)&lB[r*64 + ((kq ^ (r & 7))*8)];
      }
#pragma unroll
      for (int mt = 0; mt < 4; ++mt)
#pragma unroll
        for (int nt = 0; nt < TNW; ++nt)
          acc[mt][nt] = __builtin_amdgcn_mfma_f32_16x16x32_bf16(af[mt], bfr[nt], acc[mt][nt], 0, 0, 0);
    }
    bool own = false;
    if (EPI == 3) {
      own = ((k0 >> 6) & 3) == bxv;
      if (own) {
        // weighted column sums of this A-tile (P rows s = m0+r, cols k0+..)
        float part[8] = {0.f,0.f,0.f,0.f,0.f,0.f,0.f,0.f};
#pragma unroll
        for (int rr = 0; rr < 4; ++rr) {
          const int r = csg*4 + rr;
          bf16x8 v = *(const bf16x8*)&lA[r*64 + ((csph ^ (r & 7))*8)];
          const float li = linv4[rr];
#pragma unroll
          for (int j = 0; j < 8; ++j) part[j] += b2f(v[j]) * li;
        }
#pragma unroll
        for (int j = 0; j < 8; ++j) redcs[csg*68 + csph*8 + j] = part[j];
      }
    }
    __syncthreads();
    if (EPI == 3) {
      if (own && tid < 64) {
        float s = 0.f;
#pragma unroll
        for (int g2 = 0; g2 < 32; ++g2) s += redcs[g2*68 + tid];
        atomicAdd(&ocol[(long long)z*lda + k0 + tid], s);
      }
    }
  }

  if (EPI == 3) {
    // per-column sum^2 over m of acc * (1/l[row]); no C store; no mean-sum
    // (meanc = (1/S) sum_t cs[t]*V[c,t] in vv_fin — summation-order swap).
    // reduction scratch aliased onto dead lA (loop ended with syncthreads).
    float* red2 = (float*)lA;                 // [4][TNW][16]
    const int cr = (lane >> 4)*4;
    float linv[4][4];
#pragma unroll
    for (int mt = 0; mt < 4; ++mt)
#pragma unroll
      for (int i = 0; i < 4; ++i)
        linv[mt][i] = 1.f / rs[(long long)z*sRs + (m0 + wm*64 + mt*16 + cr + i)];
    float s2[TNW];
#pragma unroll
    for (int nt = 0; nt < TNW; ++nt) {
      s2[nt] = 0.f;
#pragma unroll
      for (int mt = 0; mt < 4; ++mt)
#pragma unroll
        for (int i = 0; i < 4; ++i) {
          float v = acc[mt][nt][i] * linv[mt][i];
          s2[nt] += v*v;
        }
      s2[nt] += __shfl_xor(s2[nt], 16, 64);
      s2[nt] += __shfl_xor(s2[nt], 32, 64);
    }
    __syncthreads();   // protect redcs reads above before lA-alias writes
    if (lane < 16) {
#pragma unroll
      for (int nt = 0; nt < TNW; ++nt)
        red2[(wvi*TNW + nt)*16 + lane] = s2[nt];
    }
    __syncthreads();
    if (tid < TN) {
      const int wn2 = tid / (TNW*16), rem = tid % (TNW*16);
      float v = red2[wn2*(TNW*16) + rem] + red2[(2+wn2)*(TNW*16) + rem];
      atomicAdd(&osum2[sCb*z + n0 + tid], v);
    }
    return;
  }

  const int cr = (lane >> 4)*4, cc = lane & 15;
#pragma unroll
  for (int mt = 0; mt < 4; ++mt) {
#pragma unroll
    for (int i = 0; i < 4; ++i) {
      const int mm = m0 + wm*64 + mt*16 + cr + i;
      float rsum = 0.f, rsum2 = 0.f;
#pragma unroll
      for (int nt = 0; nt < TNW; ++nt) {
        const int nn = n0 + wn*(TNW*16) + nt*16 + cc;
        float v = acc[mt][nt][i];
        const long long co = sC*z + (long long)mm*ldc + nn;
        if (EPI == 0) {
          v *= scale;
          if (cbias) v += cbias[sCb*z + nn];
          ((bf16*)Cout)[co] = f2b(v);
        } else if (EPI == 2) {
          v = fmaxf(v*rs[mm] + rsh[mm], 0.f);
          ((float*)Cout)[co] = v;
          rsum += v; rsum2 += v*v;
        } else if (EPI == 4) {
          v = __expf(v);
          ((bf16*)Cout)[co] = f2b(v);
          rsum += v;
        } else if (EPI == 5) {
          v = v*rs[(long long)z*sRs + mm] + rsh[(long long)z*sRs + mm]*cbias[sCb*z + nn];
          ((bf16*)Cout)[co] = f2b(v);
        }
      }
      if (EPI == 2 || EPI == 4) {
        // reduce across the 16 cc lanes (row constant there)
        rsum += __shfl_xor(rsum, 1, 64); rsum += __shfl_xor(rsum, 2, 64);
        rsum += __shfl_xor(rsum, 4, 64); rsum += __shfl_xor(rsum, 8, 64);
        if (EPI == 2) {
          rsum2 += __shfl_xor(rsum2, 1, 64); rsum2 += __shfl_xor(rsum2, 2, 64);
          rsum2 += __shfl_xor(rsum2, 4, 64); rsum2 += __shfl_xor(rsum2, 8, 64);
        }
        if (cc == 0) {
          atomicAdd(&osum[(long long)z*sRs + mm], rsum);
          if (EPI == 2) atomicAdd(&osum2[(long long)z*sRs + mm], rsum2);
        }
      }
    }
  }
}

// ---------------------------------------------------------------------------
// QK->exp specialized GEMM (r7-proven): 256x256 tile, BK=64, 512 threads
// (8 waves, 2x4), double-buffered LDS, counted vmcnt(8) (never drained in
// main loop — r8 showed drain-to-0 single-buffer costs ~7% with NO occupancy
// gain), per-phase raw s_barrier + s_setprio around each 16-MFMA cluster.
// XCD-chunked swizzle (r5: FETCH 79->24.7 MB). Epilogue: exp + row-sum
// atomics staged through dead LDS ([256][264] bf16) then full-line copy-out.
// C[m,n] = exp(sum_k Q[m,k]*K[n,k]) bf16 + per-row sum atomics into lsum.
// QK slab layout: slab = side*8 + b*2 + ph; z = ph*4 + b.
// Shapes hardcoded: M=N=2048, K=512, ld=512, ldc=2048.
// ---------------------------------------------------------------------------
__global__ void __launch_bounds__(512, 2) qk_exp_k(
    const bf16* __restrict__ QK, bf16* __restrict__ P, float* __restrict__ lsum)
{
  // buffer b: A tile [256][64] bf16 at b*65536 bytes, B tile at +32768 bytes.
  // physical chunk c of row r holds logical k-chunk c ^ (r&7)  (16B chunks)
  // epilogue reuses lds as padded C tile [256][264] bf16 = 135168 B.
  __shared__ alignas(16) char lds[135168];
  const int tid = threadIdx.x;
  const int bid = blockIdx.x;
  const int xcd = bid & 7, slot = bid >> 3;
  const int z  = (xcd >> 1) + ((slot >> 5) << 2);
  const int t  = (slot & 31) + ((xcd & 1) << 5);
  const int by = t >> 3, bx = t & 7;
  const int ph = z >> 2, b = z & 3;
  const bf16* Qb = QK + (long long)(b*2 + ph) * (2048LL*512);
  const bf16* Kb = QK + (long long)(8 + b*2 + ph) * (2048LL*512);
  const int m0 = by * 256, n0 = bx * 256;
  const int lane = tid & 63, wvi = tid >> 6;
  const int wm = wvi >> 2, wn = wvi & 3;          // 2 x 4 wave grid
  const int l15 = lane & 15, lq = lane >> 4;
  const int swz = l15 & 7;

  f32x4 acc[8][4] = {};

  // loader: 512 threads x 16B = 8KB/issue = 64 rows of 64 bf16; 4 issues/tile.
  // global source pre-swizzled so the linear LDS write lands swizzled (m173).
  const int lr = tid >> 3;
  const int lc = ((tid ^ lr) & 7) * 8;
  const bf16* pa = Qb + (long long)(m0 + lr)*512 + lc;
  const bf16* pb = Kb + (long long)(n0 + lr)*512 + lc;

  auto STAGE = [&](int bb, int kt) {
    char* da = (char*)lds + bb*65536 + tid*16;
    const bf16* ga = pa + kt*64;
    const bf16* gb = pb + kt*64;
#pragma unroll
    for (int it = 0; it < 4; ++it) gl_lds16(ga + it*64*512, da + it*8192);
#pragma unroll
    for (int it = 0; it < 4; ++it) gl_lds16(gb + it*64*512, da + 32768 + it*8192);
  };

  STAGE(0, 0);
  for (int kt = 0; kt < 8; ++kt) {
    const int cur = kt & 1;
    if (kt < 7) {
      STAGE(cur ^ 1, kt + 1);                      // 8 new loads in flight
      asm volatile("s_waitcnt vmcnt(8)" ::: "memory");   // wait only kt's 8
    } else {
      asm volatile("s_waitcnt vmcnt(0)" ::: "memory");
    }
    __builtin_amdgcn_s_barrier();                  // buf[cur] visible to all

    const bf16* lA = (const bf16*)(lds + cur*65536);
    const bf16* lB = lA + 16384;

    bf16x8 af[4], bfr[4];
    // 4 phases per K-tile: {ks0,m0-3} {ks0,m4-7} {ks1,m0-3} {ks1,m4-7}
#pragma unroll
    for (int half = 0; half < 4; ++half) {
      const int ks = half >> 1, mg = (half & 1) * 4;
      const int kq = ks*4 + lq;
      const int ko = (kq ^ swz) * 8;
      if ((half & 1) == 0) {
#pragma unroll
        for (int nt = 0; nt < 4; ++nt)
          bfr[nt] = *(const bf16x8*)&lB[(wn*64 + nt*16 + l15)*64 + ko];
      }
#pragma unroll
      for (int mt = 0; mt < 4; ++mt)
        af[mt] = *(const bf16x8*)&lA[(wm*128 + (mg + mt)*16 + l15)*64 + ko];
      __builtin_amdgcn_s_barrier();
      __builtin_amdgcn_s_setprio(1);
#pragma unroll
      for (int mt = 0; mt < 4; ++mt)
#pragma unroll
        for (int nt = 0; nt < 4; ++nt)
          acc[mg + mt][nt] = __builtin_amdgcn_mfma_f32_16x16x32_bf16(
              af[mt], bfr[nt], acc[mg + mt][nt], 0, 0, 0);
      __builtin_amdgcn_s_setprio(0);
      __builtin_amdgcn_s_barrier();
    }
  }

  // ---- epilogue (no max-sub: logits ~ N(0,1)) ------------------------------
  // Phase 1: exp + per-row sums into LDS-staged padded C tile.
  constexpr int LDC = 264;                         // bf16 row stride (528 B)
  bf16* lC = (bf16*)lds;                           // buffers dead after barrier
  const long long zT = (long long)z * 2048;
  float* lrw = lsum + zT;
  const int cr = lq * 4;
#pragma unroll
  for (int mt = 0; mt < 8; ++mt) {
#pragma unroll
    for (int i = 0; i < 4; ++i) {
      const int mmL = wm*128 + mt*16 + cr + i;
      float rsum = 0.f;
#pragma unroll
      for (int nt = 0; nt < 4; ++nt) {
        const int nnL = wn*64 + nt*16 + l15;
        float v = __expf(acc[mt][nt][i]);
        lC[mmL*LDC + nnL] = f2b(v);
        rsum += v;
      }
      rsum += __shfl_xor(rsum, 1, 64); rsum += __shfl_xor(rsum, 2, 64);
      rsum += __shfl_xor(rsum, 4, 64); rsum += __shfl_xor(rsum, 8, 64);
      if (l15 == 0) atomicAdd(&lrw[m0 + mmL], rsum);
    }
  }
  __syncthreads();
  // Phase 2: coalesced copy-out, 16B/thread/iter; 32 lanes = 512B contiguous.
  bf16* Cb = P + zT * 2048;
#pragma unroll
  for (int j = 0; j < 16; ++j) {
    const int flat = j*512 + tid;                  // 16B-chunk id in [0,8192)
    const int r = flat >> 5, c16 = flat & 31;
    const f32x4 v = *(const f32x4*)&lC[r*LDC + c16*8];
    *(f32x4*)&Cb[(long long)(m0 + r)*2048 + n0 + c16*8] = v;
  }
}

// ---------------------------------------------------------------------------
// Fused transpose + stats: reads src/trg f32 ONCE (replaces row_stats_k +
// col_stats_k + transform_k, 3x33.5MB reads -> 1x). Per (z, t0:32, c0:64)
// block: stage f32 tile in LDS, write XT bf16 in full 128B lines, reduce
// row (per z,c over t) and col (per z,t over c) sum/sumsq partials in LDS,
// atomically accumulate into rsum/rsum2/csum/csum2 (zeroed beforehand).
// ---------------------------------------------------------------------------
__global__ void __launch_bounds__(256) transform_stats_k(
    const float* __restrict__ src, const float* __restrict__ trg,
    bf16* __restrict__ XT, float* __restrict__ rsum, float* __restrict__ rsum2,
    float* __restrict__ csum, float* __restrict__ csum2)
{
  __shared__ float tile[64][33];
  __shared__ float rp1[64][4], rp2[64][4];
  __shared__ float cp1[32][8], cp2[32][8];
  const int z = blockIdx.z, t0 = blockIdx.x*32, c0 = blockIdx.y*64;
  const int is_t = z >= B_, b = z & (B_-1);
  const float* X = is_t ? trg : src;
  const int tid = threadIdx.x;
  const int tx = tid & 31, cy = tid >> 5;          // t lane, c group (8)
#pragma unroll
  for (int it = 0; it < 8; ++it) {
    const int cl = cy + it*8;
    tile[cl][tx] = X[((long long)b*C_ + c0 + cl)*T_ + t0 + tx];
  }
  __syncthreads();
  // XT write: lane packs 2 bf16 -> 4B; 32 lanes = 128B full line per t-row.
  const int l32 = tid & 31, tq = tid >> 5;
#pragma unroll
  for (int r = 0; r < 4; ++r) {
    const int tl = r*8 + tq;
    bf16 b0 = f2b(tile[2*l32][tl]), b1 = f2b(tile[2*l32+1][tl]);
    unsigned short u0, u1;
    __builtin_memcpy(&u0, &b0, 2); __builtin_memcpy(&u1, &b1, 2);
    const unsigned int pk = (unsigned int)u0 | ((unsigned int)u1 << 16);
    *(unsigned int*)&XT[((long long)z*T_ + t0 + tl)*C_ + c0 + 2*l32] = pk;
  }
  // row partials: thread (cl = tid>>2, g = tid&3) sums t = g+4k, k<8
  {
    const int cl = tid >> 2, g = tid & 3;
    float s1 = 0.f, s2 = 0.f;
#pragma unroll
    for (int k = 0; k < 8; ++k){ float v = tile[cl][g + 4*k]; s1 += v; s2 += v*v; }
    rp1[cl][g] = s1; rp2[cl][g] = s2;
  }
  // col partials: thread (tl = tid>>3, g = tid&7) sums c = g+8k, k<8
  {
    const int tl = tid >> 3, g = tid & 7;
    float s1 = 0.f, s2 = 0.f;
#pragma unroll
    for (int k = 0; k < 8; ++k){ float v = tile[g + 8*k][tl]; s1 += v; s2 += v*v; }
    cp1[tl][g] = s1; cp2[tl][g] = s2;
  }
  __syncthreads();
  if (tid < 64) {
    float s1 = rp1[tid][0]+rp1[tid][1]+rp1[tid][2]+rp1[tid][3];
    float s2 = rp2[tid][0]+rp2[tid][1]+rp2[tid][2]+rp2[tid][3];
    atomicAdd(&rsum[z*C_ + c0 + tid], s1);
    atomicAdd(&rsum2[z*C_ + c0 + tid], s2);
  } else if (tid < 96) {
    const int tl = tid - 64;
    float s1 = 0.f, s2 = 0.f;
#pragma unroll
    for (int g = 0; g < 8; ++g){ s1 += cp1[tl][g]; s2 += cp2[tl][g]; }
    atomicAdd(&csum[z*T_ + t0 + tl], s1);
    atomicAdd(&csum2[z*T_ + t0 + tl], s2);
  }
}

// ---- finalize both stat axes (ddof=1): rows (z,c) then cols (z,t) ----------
__global__ void __launch_bounds__(256) statfin_k(
    const float* __restrict__ rsum, const float* __restrict__ rsum2,
    const float* __restrict__ csum, const float* __restrict__ csum2,
    float* __restrict__ inm, float* __restrict__ ins,
    float* __restrict__ tnm, float* __restrict__ tns)
{
  const int i = blockIdx.x*256 + threadIdx.x;   // 80 blocks = 20480
  if (i < 2*B_*C_) {
    const float s1 = rsum[i], s2 = rsum2[i];
    const float m = s1 * (1.f/T_);
    const float var = (s2 - s1*m) * (1.f/(T_-1));
    inm[i] = m; ins[i] = sqrtf(fmaxf(var, 0.f));
  } else {
    const int j = i - 2*B_*C_;
    const float s1 = csum[j], s2 = csum2[j];
    const float m = s1 * (1.f/C_);
    const float var = (s2 - s1*m) * (1.f/(C_-1));
    tnm[j] = m; tns[j] = sqrtf(fmaxf(var, 0.f));
  }
}

// ---- fold norm into QK projection weights + biases -------------------------
// W[z][o][c], cb[z][o]; z = side*8 + b*2 + ph (side 0=Q/src, 1=K/trg)
// ph0 (CAN/inorm): W = w*sc/(is+eps), cb = -sum_c W*im   (epilogue rs=rsh=1)
// ph1 (TAN/tinorm): W = w*sc,         cb = sum_c W       (row-affine epi)
__global__ void __launch_bounds__(256) foldqk_k(
    const float* __restrict__ wq_c, const float* __restrict__ wq_t,
    const float* __restrict__ wk_c, const float* __restrict__ wk_t,
    const float* __restrict__ inm, const float* __restrict__ ins,
    bf16* __restrict__ W, float* __restrict__ cb)
{
  __shared__ float r1[4];
  const int o = blockIdx.x, z = blockIdx.y;
  const int side = z >> 3, b = (z >> 1) & 3, ph = z & 1;
  const float* w = side ? (ph ? wk_t : wk_c) : (ph ? wq_t : wq_c);
  const float sc = side ? 1.f : 0.044194173824159216f;   // 1/sqrt(C) on Q
  const int ofs = (side*B_ + b)*C_;
  float acc = 0.f;
  for (int c = threadIdx.x; c < C_; c += 256) {
    float wv = w[o*C_ + c] * sc;
    float out, contrib;
    if (ph == 0) {
      float ri = 1.f / (ins[ofs + c] + EPSF);
      out = wv * ri;
      contrib = -out * inm[ofs + c];
    } else {
      out = wv;
      contrib = wv;
    }
    W[((long long)z*C_ + o)*C_ + c] = f2b(out);
    acc += contrib;
  }
  acc = wave_sum(acc);
  const int lane = threadIdx.x & 63, wq = threadIdx.x >> 6;
  if (!lane) r1[wq] = acc;
  __syncthreads();
  if (threadIdx.x == 0) cb[z*C_ + o] = r1[0]+r1[1]+r1[2]+r1[3];
}

// ---- per-z row scale/shift for EPI 5 ---------------------------------------
__global__ void __launch_bounds__(256) rsfill_k(
    const float* __restrict__ tnm, const float* __restrict__ tns,
    float* __restrict__ rsq, float* __restrict__ rshq)
{
  const int z = blockIdx.y, t = blockIdx.x*256 + threadIdx.x;  // grid (8,16)
  const int side = z >> 3, b = (z >> 1) & 3, ph = z & 1;
  float rv, rh;
  if (ph == 0) { rv = 1.f; rh = 1.f; }
  else {
    const int ofs = (side*B_ + b)*T_;
    float r = 1.f / (tns[ofs + t] + EPSF);
    rv = r; rh = -tnm[ofs + t] * r;
  }
  rsq[z*T_ + t] = rv; rshq[z*T_ + t] = rh;
}

// ---- fp32 row softmax (SAP) ------------------------------------------------
__global__ void __launch_bounds__(256) softmax_row_k(const float* __restrict__ X, float* __restrict__ O)
{
  __shared__ float red[4];
  const long long row = blockIdx.x;
  const float* x = X + row*T_ + threadIdx.x*8;
  float v[8];
  f32x4 a0 = *(const f32x4*)x;
  f32x4 a1 = *(const f32x4*)(x + 4);
#pragma unroll
  for (int j = 0; j < 4; ++j){ v[j] = a0[j]; v[4+j] = a1[j]; }
  float m = -3.4e38f;
#pragma unroll
  for (int j = 0; j < 8; ++j) m = fmaxf(m, v[j]);
  m = wave_max(m);
  const int lane = threadIdx.x & 63, w = threadIdx.x >> 6;
  if (!lane) red[w] = m;
  __syncthreads();
  m = fmaxf(fmaxf(red[0], red[1]), fmaxf(red[2], red[3]));
  __syncthreads();
  float s = 0.f;
#pragma unroll
  for (int j = 0; j < 8; ++j){ v[j] = __expf(v[j] - m); s += v[j]; }
  s = wave_sum(s);
  if (!lane) red[w] = s;
  __syncthreads();
  s = red[0]+red[1]+red[2]+red[3];
  const float inv = 1.f/s;
  float* o = O + row*T_ + threadIdx.x*8;
#pragma unroll
  for (int j = 0; j < 8; ++j) o[j] = v[j]*inv;
}

// ---- vv-GEMV: meanc = (1/S) sum_t cs[t]*V[c,t]  (colsum identity),
//      stdc from m2sum + sum_t cs[t]*V^2; z in [0,2B) ------------------------
__global__ void __launch_bounds__(256) vv_fin_k(const float* __restrict__ cs,
    const bf16* __restrict__ VT,
    const float* __restrict__ m2sum, float* __restrict__ meanc, float* __restrict__ stdc)
{
  __shared__ float r1[4], r2[4];
  const int c = blockIdx.x, z = blockIdx.y;
  const bf16* vr = VT + ((long long)z*C_ + c)*T_;
  const float* w = cs + z*T_;
  float a1 = 0.f, a2 = 0.f;
  for (int t = threadIdx.x; t < T_; t += 256){
    float v = b2f(vr[t]); float wt = w[t];
    a1 += wt*v; a2 += wt*v*v;
  }
  a1 = wave_sum(a1); a2 = wave_sum(a2);
  const int lane = threadIdx.x & 63, wq = threadIdx.x >> 6;
  if (!lane){ r1[wq] = a1; r2[wq] = a2; }
  __syncthreads();
  if (threadIdx.x == 0){
    a1 = r1[0]+r1[1]+r1[2]+r1[3];
    a2 = r2[0]+r2[1]+r2[2]+r2[3];
    const int idx = z*C_ + c;
    meanc[idx] = a1 * (1.f/S_);
    float var = (a2 - m2sum[idx]) * (1.f/S_);
    stdc[idx] = sqrtf(fmaxf(var, 0.f));
  }
}

// ---- fold adaptive-norm epilogue + concat + inorm(src) into conv1 weights --
__global__ void __launch_bounds__(256) weff_k(const float* __restrict__ w1,
    const float* __restrict__ b1, const float* __restrict__ sdt, const float* __restrict__ sdc,
    const float* __restrict__ mct, const float* __restrict__ mcc,
    const float* __restrict__ inm, const float* __restrict__ ins,
    bf16* __restrict__ Weff, float* __restrict__ beff)
{
  __shared__ float r1[4];
  const int o = blockIdx.x, b = blockIdx.y;
  const int ofs = b*C_;                       // src inorm slab
  float accb = 0.f;
  for (int c = threadIdx.x; c < C_; c += 256) {
    float wa = w1[o*2*C_ + c], wb = w1[o*2*C_ + C_ + c];
    float s = wa*sdt[b*C_+c] + wb*sdc[b*C_+c];
    float w2 = s / (ins[ofs + c] + EPSF);
    Weff[((long long)(b*C_ + o))*C_ + c] = f2b(w2);
    accb += wa*mct[b*C_+c] + wb*mcc[b*C_+c] - w2*inm[ofs + c];
  }
  accb = wave_sum(accb);
  const int lane = threadIdx.x & 63, w = threadIdx.x >> 6;
  if (!lane) r1[w] = accb;
  __syncthreads();
  if (threadIdx.x == 0) beff[b*C_ + o] = b1[o] + r1[0]+r1[1]+r1[2]+r1[3];
}

// ---- conv2 weight reorder (k = dt*C + c) + BN scale/shift ------------------
__global__ void __launch_bounds__(256) w2r_k(const float* __restrict__ w2,
    const float* __restrict__ g, const float* __restrict__ be,
    const float* __restrict__ mu, const float* __restrict__ va,
    bf16* __restrict__ W2r, float* __restrict__ bnsc, float* __restrict__ bnsh)
{
  const int o = blockIdx.x;
  for (int c = threadIdx.x; c < C_; c += 256)
#pragma unroll
    for (int dt = 0; dt < 3; ++dt)
      W2r[(long long)o*3*C_ + dt*C_ + c] = f2b(w2[((long long)o*C_ + c)*3 + dt]);
  if (threadIdx.x == 0) {
    float s = g[o] * rsqrtf(va[o] + EPSF);
    bnsc[o] = s;
    bnsh[o] = be[o] - mu[o]*s;
  }
}

// ---- cast wv_c, wv_t to bf16 -----------------------------------------------
__global__ void __launch_bounds__(256) castv_k(const float* __restrict__ a0,
    const float* __restrict__ a1, bf16* __restrict__ o)
{
  const int i = blockIdx.x*256 + threadIdx.x;   // 2*262144
  o[i] = f2b(((i >> 18) ? a1 : a0)[i & 262143]);
}

// ---- zero pad rows of x1p --------------------------------------------------
__global__ void __launch_bounds__(256) zero_pad_k(bf16* __restrict__ x1p)
{
  const int i = blockIdx.x*256 + threadIdx.x;   // 4096
  const int b = i >> 10, rem = i & 1023;
  const long long row = (rem >> 9) ? (T_+1) : 0;
  const int c = rem & (C_-1);
  x1p[((long long)b*(T_+2) + row)*C_ + c] = f2b(0.f);
}

__global__ void __launch_bounds__(256) zero_f32_k(float* __restrict__ p)
{
  p[blockIdx.x*256 + threadIdx.x] = 0.f;
}

// ---- SAP: logits (means for z<B, stds for z>=B) ----------------------------
__global__ void __launch_bounds__(256) sap_logit_k(const float* __restrict__ means,
    const float* __restrict__ stds, const float* __restrict__ mw, const float* __restrict__ sw,
    const float* __restrict__ mb, const float* __restrict__ sb, float* __restrict__ out)
{
  const int n = blockIdx.x*4 + (threadIdx.x >> 6);
  const int z = blockIdx.y;
  const int sel = z >= B_, b = z & (B_-1);
  const float* x = sel ? stds : means;
  const float* w = sel ? sw : mw;
  const int lane = threadIdx.x & 63;
  const float* p = x + ((long long)b*S_ + n)*C_;
  float a = 0.f;
  for (int c = lane; c < C_; c += 64) a += p[c]*w[c];
  a = wave_sum(a);
  if (!lane) out[z*S_ + n] = a + (sel ? sb[0] : mb[0]);
}

// ---- SAP: weighted sum over n (chunked, atomic), z in [0,2B) ---------------
__global__ void __launch_bounds__(256) sap_wsum_k(const float* __restrict__ means,
    const float* __restrict__ stds, const float* __restrict__ a, float* __restrict__ out)
{
  const int c = blockIdx.x*256 + threadIdx.x;
  const int z = blockIdx.z;
  const int sel = z >= B_, b = z & (B_-1);
  const float* x = sel ? stds : means;
  const long long n0 = (long long)blockIdx.y*256;
  const float* p = x + ((long long)b*S_ + n0)*C_ + c;
  const float* aw = a + z*S_ + n0;
  float acc = 0.f;
  for (int n = 0; n < 256; ++n) acc += p[(long long)n*C_] * aw[n];
  atomicAdd(&out[z*C_ + c], acc);
}

// ---- final: inorm(y)*sap_std + sap_mean, stats from raw sums ---------------
__global__ void __launch_bounds__(256) final_k(const float* __restrict__ y,
    const float* __restrict__ ysum, const float* __restrict__ y2sum,
    const float* __restrict__ sapms, float* __restrict__ out)
{
  const long long i = (long long)(blockIdx.x*256 + threadIdx.x) * 4;
  const long long r = i >> 11;
  const float s1 = ysum[r], s2 = y2sum[r];
  const float m = s1 * (1.f/T_);
  const float var = (s2 - s1*m) * (1.f/(T_-1));
  const float inv = 1.f/(sqrtf(fmaxf(var, 0.f)) + EPSF);
  const float mn = sapms[r], sd = sapms[B_*C_ + r];
  const f32x4 v = *(const f32x4*)(y + i);
  f32x4 o;
#pragma unroll
  for (int j = 0; j < 4; ++j) o[j] = (v[j] - m)*inv*sd + mn;
  *(f32x4*)(out + i) = o;
}

// ---------------------------------------------------------------------------
extern "C" void kernel_launch(void* const* d_in, const int* in_sizes, int n_in,
                              void* d_out, int out_size, void* d_ws, size_t ws_size,
                              hipStream_t stream)
{
  (void)in_sizes; (void)n_in; (void)out_size; (void)ws_size;
  const float* src    = (const float*)d_in[0];
  const float* trg    = (const float*)d_in[1];
  const float* means  = (const float*)d_in[2];
  const float* stds   = (const float*)d_in[3];
  const float* conv1w = (const float*)d_in[10];
  const float* conv1b = (const float*)d_in[11];
  const float* conv2w = (const float*)d_in[12];
  const float* bn_g   = (const float*)d_in[13];
  const float* bn_b   = (const float*)d_in[14];
  const float* bn_m   = (const float*)d_in[15];
  const float* bn_v   = (const float*)d_in[16];
  const float* msap_w = (const float*)d_in[17];
  const float* msap_b = (const float*)d_in[18];
  const float* ssap_w = (const float*)d_in[19];
  const float* ssap_b = (const float*)d_in[20];

  const long long BTC = (long long)B_*T_*C_;   // 4194304 elems
  const long long TC  = (long long)T_*C_;      // 1048576 elems

  char* p = (char*)d_ws;
  auto take = [&](size_t n)->char*{ char* r = p; p += (n + 255) & ~(size_t)255; return r; };

  // Phase convention: p=0 -> CAN (inorm), p=1 -> TAN (tinorm); z = p*B + b.
  bf16* P2  = (bf16*)take((size_t)2*B_*S_*T_*2);           // 64 MB (exp logits)
  bf16* QK4 = (bf16*)take((size_t)16*TC*2);                // 32 MB (16 slabs)
  bf16* VT2 = (bf16*)take((size_t)2*BTC*2);                // 16 MB [2][B][C][T]
  bf16* WQeff = (bf16*)take((size_t)16*C_*C_*2);           // 8 MB folded wq/wk
  bf16* WVb = (bf16*)take((size_t)2*C_*C_*2);              // 1 MB wv bf16
  bf16* Weff= (bf16*)take((size_t)B_*C_*C_*2);
  bf16* W2r = (bf16*)take((size_t)C_*3*C_*2);
  bf16* x1p = (bf16*)take((size_t)B_*(T_+2)*C_*2);
  float* y  = (float*)take((size_t)B_*C_*T_*4);            // 16 MB
  bf16* XT  = (bf16*)y;   // alias: XT (raw transposes, 16 MB) dead before
                          // conv2 writes y; lifetimes are stream-disjoint.
  // contiguous zero block: colsum..y2sum (49152) + rsum/rsum2/csum/csum2
  // (40960) = 90112 elems -> 352 blocks of zero_f32_k.
  float* colsum = (float*)take(2*B_*T_*4);                 // 16384 elems
  float* msum   = (float*)take(2*B_*C_*4);                 // 4096 (unused now)
  float* m2sum  = (float*)take(2*B_*C_*4);                 // 4096
  float* sapms  = (float*)take(2*B_*C_*4);                 // 4096
  float* lrow   = (float*)take(2*B_*S_*4);                 // 16384
  float* ysum   = (float*)take(B_*C_*4);                   // 2048
  float* y2sum  = (float*)take(B_*C_*4);                   // 2048
  float* rsum   = (float*)take(2*B_*C_*4);                 // 4096
  float* rsum2  = (float*)take(2*B_*C_*4);                 // 4096
  float* csum   = (float*)take(2*B_*T_*4);                 // 16384
  float* csum2  = (float*)take(2*B_*T_*4);                 // 16384 => 90112
  float* tnm = (float*)take(2*B_*T_*4);
  float* tns = (float*)take(2*B_*T_*4);
  float* inm = (float*)take(2*B_*C_*4);
  float* ins = (float*)take(2*B_*C_*4);
  float* meanc = (float*)take(2*B_*C_*4);                  // [2][B][C]
  float* stdc  = (float*)take(2*B_*C_*4);
  float* beff  = (float*)take(B_*C_*4);
  float* bnsc  = (float*)take(C_*4);
  float* bnsh  = (float*)take(C_*4);
  float* sapl  = (float*)take(2*B_*S_*4);
  float* sapa  = (float*)take(2*B_*S_*4);
  float* cbq   = (float*)take(16*C_*4);                    // folded biases
  float* rsq   = (float*)take(16*T_*4);                    // row scales
  float* rshq  = (float*)take(16*T_*4);                    // row shifts
  (void)msum;

  dim3 blk(256);

  zero_f32_k<<<352, blk, 0, stream>>>(colsum);    // colsum..csum2 = 90112
  castv_k<<<2048, blk, 0, stream>>>((const float*)d_in[9], (const float*)d_in[6], WVb);
  w2r_k<<<C_, blk, 0, stream>>>(conv2w, bn_g, bn_b, bn_m, bn_v, W2r, bnsc, bnsh);
  // fused transpose + both stat axes (single pass over src/trg)
  transform_stats_k<<<dim3(T_/32, C_/64, 2*B_), blk, 0, stream>>>(src, trg, XT,
      rsum, rsum2, csum, csum2);
  statfin_k<<<80, blk, 0, stream>>>(rsum, rsum2, csum, csum2, inm, ins, tnm, tns);
  foldqk_k<<<dim3(C_, 16), blk, 0, stream>>>((const float*)d_in[7], (const float*)d_in[4],
      (const float*)d_in[8], (const float*)d_in[5], inm, ins, WQeff, cbq);
  rsfill_k<<<dim3(T_/256, 16), blk, 0, stream>>>(tnm, tns, rsq, rshq);
  zero_pad_k<<<16, blk, 0, stream>>>(x1p);

  // QKV projections on RAW transposed panels with norm-fold epilogue (EPI 5).
  // z in [0,16): A = XT slab z/2 (src b0..3, trg b0..3), B/epi slab z.
  // XCD-chunked: xcd owns z = {2*xcd, 2*xcd+1} -> shared XT slab L2-resident.
  gemm_nt<5,4,4,16,16><<<dim3(1024), blk, 0, stream>>>(XT, WQeff, QK4,
      C_, C_, C_, C_, TC, (long long)C_*C_, TC, C_,
      2, 16, 1.f, rsq, rshq, cbq, nullptr, nullptr, T_, nullptr);
  // V^T[z] = wv[p] @ trg[b]^T -> [C,T]; z in [0,8): p=z/4, b=z%4
  // XCD-chunked: xcd = z -> trg XT slab + weight slab L2-resident.
  gemm_nt<0,2,32,4,8><<<dim3(1024), blk, 0, stream>>>(WVb, XT + 4*TC, VT2,
      C_, C_, C_, T_, (long long)C_*C_, TC, (long long)C_*T_, 0, 4, 4, 1.f,
      nullptr, nullptr, nullptr, nullptr, nullptr, 0, nullptr);
  // P' = exp(Q @ K^T) bf16 + row sums l (no max-sub: logits ~ N(0,1))
  // 256^2-tile 8-wave double-buffered pipeline (counted vmcnt), XCD-chunked
  qk_exp_k<<<dim3(512), dim3(512), 0, stream>>>(QK4, P2, lrow);
  // PV with fused (1/l)-scaled sum_s^2 epilogue (m2sum; no output store)
  // + fused colsum of P'/l over s into colsum (mean path via identity)
  // XCD-chunked: xcd = z -> P panels read once into L2, 4 c-blocks hit.
  gemm_nt<3,4,4,16,8><<<dim3(512), blk, 0, stream>>>(P2, VT2, nullptr,
      T_, T_, T_, 0, (long long)S_*T_, (long long)C_*T_, 0, C_, 1, 8, 1.f,
      lrow, nullptr, nullptr, nullptr, m2sum, S_, colsum);
  vv_fin_k<<<dim3(C_, 2*B_), blk, 0, stream>>>(colsum, VT2, m2sum, meanc, stdc);

  // conv1 folded with adaptive-norm + inorm(src) epilogues on raw XT
  weff_k<<<dim3(C_, B_), blk, 0, stream>>>(conv1w, conv1b,
      stdc + B_*C_, stdc, meanc + B_*C_, meanc, inm, ins, Weff, beff);
  // XCD-chunked: xcd pair shares z -> src XT slab + Weff slab L2-resident.
  gemm_nt<0,2,8,16,4><<<dim3(512), blk, 0, stream>>>(XT, Weff, x1p + C_,
      C_, C_, C_, C_, TC, (long long)C_*C_, (long long)(T_+2)*C_, C_,
      1, 8, 1.f, nullptr, nullptr, beff, nullptr, nullptr, 0, nullptr);
  // conv2 (k=3) as overlapping-row NT GEMM + BN+ReLU + fused row-stat sums
  gemm_nt<2,2,32,4,4><<<dim3(512), blk, 0, stream>>>(W2r, x1p, y,
      3*C_, 3*C_, C_, T_, 0, (long long)(T_+2)*C_, (long long)C_*T_, 0,
      1, 8, 1.f, bnsc, bnsh, nullptr, ysum, y2sum, C_, nullptr);

  sap_logit_k<<<dim3(S_/4, 2*B_), blk, 0, stream>>>(means, stds, msap_w, ssap_w,
      msap_b, ssap_b, sapl);
  softmax_row_k<<<2*B_, blk, 0, stream>>>(sapl, sapa);
  sap_wsum_k<<<dim3(C_/256, S_/256, 2*B_), blk, 0, stream>>>(means, stds, sapa, sapms);

  final_k<<<4096, blk, 0, stream>>>(y, ysum, y2sum, sapms, (float*)d_out);
}